// Round 5
// baseline (119.965 us; speedup 1.0000x reference)
//
#include <hip/hip_runtime.h>

#define H_TOKN 57
#define OUT_HW 800
#define NMASK 64
#define C_IN 768
#define C8N 96
#define L_OUT 21
#define NPIX 3249          // 57*57
#define M_TOT 6498         // 2*3249
#define YSTR 24            // padded channel stride for y57
#define SCALE (57.0f/800.0f)

// fused conv
#define BM 64
#define ESTR 40            // bf16 LDS row stride
#define HSTR 97            // f32 LDS row stride

// binsum (direct segment-sum via tap-weight binning)
#define TILE_H 100
#define TILE_W 100
#define ROWS_T2 10
#define COLS_T2 10
#define NTAPS 100          // ROWS_T2*COLS_T2
#define SWSTR 101          // per-mask tap-weight stride (odd -> bank spread)
#define YTSTR 24           // ytile channel stride (96B, f4-aligned)

// final
#define RCSTR 28           // rowC stride (112B: 16B-aligned, 8-way bank offsets)
#define MFSTR 28

#define NSUM (2*NMASK*YSTR + 2*NMASK)   // sums + cnts, contiguous

static __device__ __forceinline__ unsigned short f2bf(float f) {
  unsigned u = __float_as_uint(f);
  u += 0x7FFFu + ((u >> 16) & 1u);   // RTNE
  return (unsigned short)(u >> 16);
}

// ---------- Kernel A (fused): y57 = pad21_24( relu(e@w1^T + b1) @ w2^T ) ----------
// conv1 via bf16 MFMA (f32 accumulate), conv2 fused in epilogue from LDS.
// Block 0 also zeroes the sums/cnts atomic accumulators (consumed by binsum next).
__global__ __launch_bounds__(256) void fused_conv_kernel(
    const float* __restrict__ e, const float* __restrict__ w1,
    const float* __restrict__ b1, const float* __restrict__ w2,
    float* __restrict__ y57, float* __restrict__ sums_base)
{
  using bf16x8 = __attribute__((ext_vector_type(8))) short;
  using f32x4  = __attribute__((ext_vector_type(4))) float;
  __shared__ __align__(16) unsigned short eA[BM * ESTR];
  __shared__ __align__(16) unsigned short wB[C8N * ESTR];
  __shared__ __align__(16) float h_lds[BM * HSTR];
  __shared__ float w2_lds[L_OUT * C8N];
  __shared__ float b1_lds[C8N];

  const int tid = threadIdx.x;
  const int m0 = blockIdx.x * BM;
  const int lane = tid & 63;
  const int wv = tid >> 6;
  const int l15 = lane & 15;
  const int khi = (lane >> 4) << 3;   // 0,8,16,24

  if (blockIdx.x == 0)
    for (int i = tid; i < NSUM; i += 256) sums_base[i] = 0.f;

  for (int i = tid; i < L_OUT * C8N; i += 256) w2_lds[i] = w2[i];
  if (tid < C8N) b1_lds[tid] = b1[tid];

  f32x4 acc[6];
  #pragma unroll
  for (int t = 0; t < 6; ++t) acc[t] = (f32x4){0.f, 0.f, 0.f, 0.f};

  for (int k0 = 0; k0 < C_IN; k0 += 32) {
    __syncthreads();
    #pragma unroll
    for (int q = 0; q < 2; ++q) {
      int f = tid + q * 256;
      int r = f >> 3, c4 = (f & 7) << 2;
      int p = m0 + r; if (p >= M_TOT) p = M_TOT - 1;
      float4 v = *(const float4*)(e + (size_t)p * C_IN + k0 + c4);
      ushort4 s; s.x = f2bf(v.x); s.y = f2bf(v.y); s.z = f2bf(v.z); s.w = f2bf(v.w);
      *(ushort4*)&eA[r * ESTR + c4] = s;
    }
    #pragma unroll
    for (int q = 0; q < 3; ++q) {
      int f = tid + q * 256;
      int r = f >> 3, c4 = (f & 7) << 2;
      float4 v = *(const float4*)(w1 + (size_t)r * C_IN + k0 + c4);
      ushort4 s; s.x = f2bf(v.x); s.y = f2bf(v.y); s.z = f2bf(v.z); s.w = f2bf(v.w);
      *(ushort4*)&wB[r * ESTR + c4] = s;
    }
    __syncthreads();
    bf16x8 a = *(bf16x8*)&eA[(wv * 16 + l15) * ESTR + khi];
    #pragma unroll
    for (int t = 0; t < 6; ++t) {
      bf16x8 b = *(bf16x8*)&wB[(t * 16 + l15) * ESTR + khi];
      acc[t] = __builtin_amdgcn_mfma_f32_16x16x32_bf16(a, b, acc[t], 0, 0, 0);
    }
  }
  __syncthreads();
  // h = relu(acc + b1) into LDS.  D: col=lane&15, row=4*(lane>>4)+reg
  #pragma unroll
  for (int t = 0; t < 6; ++t) {
    int n = t * 16 + l15;
    float bv = b1_lds[n];
    #pragma unroll
    for (int r = 0; r < 4; ++r) {
      int pl = wv * 16 + ((lane >> 4) << 2) + r;
      h_lds[pl * HSTR + n] = fmaxf(acc[t][r] + bv, 0.f);
    }
  }
  __syncthreads();
  // y57[p][l] = h[p][:] . w2[l][:]  (l=21..23 pads -> 0)
  for (int i = tid; i < BM * 24; i += 256) {
    int px = i & (BM - 1), l = i >> 6;
    float s = 0.f;
    if (l < L_OUT) {
      const float* hr = &h_lds[px * HSTR];
      const float* wr = &w2_lds[l * C8N];
      #pragma unroll 8
      for (int c = 0; c < C8N; ++c) s += hr[c] * wr[c];
    }
    int p = m0 + px;
    if (p < M_TOT) y57[(size_t)p * YSTR + l] = s;
  }
}

// ---------- Kernel B: direct segment sums via tap-weight binning ----------
// Per 100x100 output tile: bin bilinear weights into s_w[64][taps] (LDS atomics),
// then contract against the LDS-staged y-tap tile and flush global atomics.
__global__ __launch_bounds__(256) void binsum_kernel(
    const int* __restrict__ labels, const float* __restrict__ y57,
    float* __restrict__ sums, float* __restrict__ cnts)
{
  __shared__ float s_w[NMASK * SWSTR];     // ~25.9 KB
  __shared__ __align__(16) float ytile[NTAPS * YTSTR];  // 9.6 KB
  const int tid = threadIdx.x;
  const int wc0 = blockIdx.x * TILE_W;
  const int hr0 = blockIdx.y * TILE_H;
  const int b = blockIdx.z;

  for (int i = tid; i < NMASK * SWSTR; i += 256) s_w[i] = 0.f;

  float thb = fminf(fmaxf((hr0 + 0.5f) * SCALE - 0.5f, 0.f), 56.f);
  const int ib = min((int)thb, 55);
  float twb = fminf(fmaxf((wc0 + 0.5f) * SCALE - 0.5f, 0.f), 56.f);
  const int jb = min((int)twb, 55);

  const float* yb = y57 + (size_t)b * NPIX * YSTR;
  for (int i = tid; i < NTAPS * YTSTR; i += 256) {
    int t = i / YTSTR, c = i - t * YTSTR;
    int r = t / COLS_T2, cc = t - r * COLS_T2;
    int I = min(ib + r, 56), J = min(jb + cc, 56);  // OOB taps have zero weight
    ytile[i] = yb[((size_t)I * H_TOKN + J) * YSTR + c];
  }
  __syncthreads();

  const int* lb = labels + (size_t)b * OUT_HW * OUT_HW;
  const int NG = TILE_H * (TILE_W / 4);   // 2500 4-px groups
  for (int g = tid; g < NG; g += 256) {
    int dh = g / (TILE_W / 4);
    int dw4 = (g - dh * (TILE_W / 4)) * 4;
    int hh = hr0 + dh, ww0 = wc0 + dw4;
    float th = fminf(fmaxf((hh + 0.5f) * SCALE - 0.5f, 0.f), 56.f);
    int i0 = min((int)th, 55);
    float fh = th - (float)i0;
    int rowoff = (i0 - ib) * COLS_T2;
    int4 la = *(const int4*)(lb + (size_t)hh * OUT_HW + ww0);
    #define PXB(K, CMP) { \
      float tw = fminf(fmaxf((ww0 + K + 0.5f) * SCALE - 0.5f, 0.f), 56.f); \
      int j0 = min((int)tw, 55); \
      float fw = tw - (float)j0; \
      int m = la.CMP & (NMASK - 1); \
      float* sm = s_w + m * SWSTR + rowoff + (j0 - jb); \
      float w11 = fh * fw, w10 = fh - w11, w01 = fw - w11; \
      float w00 = 1.f - fh - fw + w11; \
      unsafeAtomicAdd(sm, w00); unsafeAtomicAdd(sm + 1, w01); \
      unsafeAtomicAdd(sm + COLS_T2, w10); unsafeAtomicAdd(sm + COLS_T2 + 1, w11); }
    PXB(0, x) PXB(1, y) PXB(2, z) PXB(3, w)
    #undef PXB
  }
  __syncthreads();

  // items 0..383: (m, l-quad) float4 partial sums; 384..447: counts
  for (int it = tid; it < 448; it += 256) {
    if (it < 384) {
      int m = it / 6, lq = (it - m * 6) * 4;
      const float* swm = s_w + m * SWSTR;
      float4 a = make_float4(0.f, 0.f, 0.f, 0.f);
      #pragma unroll 4
      for (int t = 0; t < NTAPS; ++t) {
        float wv = swm[t];
        float4 yv = *(const float4*)&ytile[t * YTSTR + lq];
        a.x += wv * yv.x; a.y += wv * yv.y; a.z += wv * yv.z; a.w += wv * yv.w;
      }
      float* dst = sums + ((size_t)(b * NMASK + m)) * YSTR + lq;
      unsafeAtomicAdd(dst + 0, a.x); unsafeAtomicAdd(dst + 1, a.y);
      unsafeAtomicAdd(dst + 2, a.z); unsafeAtomicAdd(dst + 3, a.w);
    } else {
      int m = it - 384;
      const float* swm = s_w + m * SWSTR;
      float c = 0.f;
      for (int t = 0; t < NTAPS; ++t) c += swm[t];
      unsafeAtomicAdd(&cnts[b * NMASK + m], c);
    }
  }
}

// ---------- Kernel C: out[b][l][hh][w] = lerp_w(rowC)[l] + meanF[label][l] ----------
// rowC = ifh*row(i0) + fh*row(i0+1) collapsed once per block; meanF = mean + b2.
__global__ __launch_bounds__(256) void final_kernel(
    const float* __restrict__ y57, const int* __restrict__ labels,
    const float* __restrict__ sums, const float* __restrict__ cnts,
    const float* __restrict__ b2, float* __restrict__ out)
{
  __shared__ __align__(16) float rowC[H_TOKN * RCSTR];
  __shared__ __align__(16) float meanF[NMASK * MFSTR];
  const int tid = threadIdx.x;
  const int hh = blockIdx.y;
  const int b = blockIdx.z;
  float th = fminf(fmaxf((hh + 0.5f) * SCALE - 0.5f, 0.f), 56.f);
  int i0 = min((int)th, 55);
  float fh = th - (float)i0;
  const float ifh = 1.f - fh;
  const float* r0 = y57 + ((size_t)b * NPIX + (size_t)i0 * H_TOKN) * YSTR;
  const float* r1 = r0 + H_TOKN * YSTR;
  for (int i = tid; i < H_TOKN * 24; i += 256) {
    int r = i / 24, c = i - r * 24;
    rowC[r * RCSTR + c] = ifh * r0[i] + fh * r1[i];
  }
  for (int i = tid; i < NMASK * L_OUT; i += 256) {
    int m = i / L_OUT, l = i - m * L_OUT;
    meanF[m * MFSTR + l] =
        sums[((size_t)(b * NMASK + m)) * YSTR + l] / fmaxf(cnts[b * NMASK + m], 1.f)
        + b2[l];
  }
  __syncthreads();
  if (tid < 200) {
    const int w0 = tid * 4;
    const int* lrow = labels + ((size_t)b * OUT_HW + hh) * OUT_HW;
    int4 la = *(const int4*)(lrow + w0);
    float* ob = out + (size_t)b * L_OUT * OUT_HW * OUT_HW + (size_t)hh * OUT_HW + w0;
    float4 accv[L_OUT];
    #define PXF(K, CMP) { \
      float tw = fminf(fmaxf((w0 + K + 0.5f) * SCALE - 0.5f, 0.f), 56.f); \
      int j0 = min((int)tw, 55); \
      float fw = tw - (float)j0; \
      int m = la.CMP & (NMASK - 1); \
      const float* c0 = &rowC[j0 * RCSTR]; \
      const float* c1 = c0 + RCSTR; \
      const float* mf = &meanF[m * MFSTR]; \
      _Pragma("unroll") \
      for (int q = 0; q < 6; ++q) { \
        float4 A = *(const float4*)(c0 + 4 * q); \
        float4 Bv = *(const float4*)(c1 + 4 * q); \
        float4 Mv = *(const float4*)(mf + 4 * q); \
        if (4 * q + 0 < L_OUT) accv[4 * q + 0].CMP = A.x + fw * (Bv.x - A.x) + Mv.x; \
        if (4 * q + 1 < L_OUT) accv[4 * q + 1].CMP = A.y + fw * (Bv.y - A.y) + Mv.y; \
        if (4 * q + 2 < L_OUT) accv[4 * q + 2].CMP = A.z + fw * (Bv.z - A.z) + Mv.z; \
        if (4 * q + 3 < L_OUT) accv[4 * q + 3].CMP = A.w + fw * (Bv.w - A.w) + Mv.w; \
      } }
    PXF(0, x) PXF(1, y) PXF(2, z) PXF(3, w)
    #undef PXF
    #pragma unroll
    for (int l = 0; l < L_OUT; ++l)
      *(float4*)(ob + (size_t)l * (OUT_HW * OUT_HW)) = accv[l];
  }
}

extern "C" void kernel_launch(void* const* d_in, const int* in_sizes, int n_in,
                              void* d_out, int out_size, void* d_ws, size_t ws_size,
                              hipStream_t stream)
{
  const float* e   = (const float*)d_in[0];
  const int*   lab = (const int*)d_in[1];
  const float* w1  = (const float*)d_in[2];
  const float* b1  = (const float*)d_in[3];
  const float* w2  = (const float*)d_in[4];
  const float* b2  = (const float*)d_in[5];
  float* out = (float*)d_out;
  float* ws  = (float*)d_ws;

  float* y57_ws = ws;                                   // 6498*24 f32
  float* sums   = y57_ws + (size_t)M_TOT * YSTR;        // 2*64*24 f32
  float* cnts   = sums + 2 * NMASK * YSTR;              // 2*64 f32 (contiguous)

  fused_conv_kernel<<<dim3((M_TOT + BM - 1) / BM), 256, 0, stream>>>(
      e, w1, b1, w2, y57_ws, sums);
  binsum_kernel<<<dim3(OUT_HW / TILE_W, OUT_HW / TILE_H, 2), 256, 0, stream>>>(
      lab, y57_ws, sums, cnts);
  final_kernel<<<dim3(1, OUT_HW, 2), 256, 0, stream>>>(
      y57_ws, lab, sums, cnts, b2, out);
}